// Round 8
// baseline (255.347 us; speedup 1.0000x reference)
//
#include <hip/hip_runtime.h>

// ---- problem constants ----
#define N_ROWS 16384   // 8*16*128
#define DIM    256
#define K_CODES 8192

// output layout (flat float32, return order)
#define OFF_ZQ   0
#define OFF_LOSS 4194304
#define OFF_IDX  4194305
#define OFF_CB   4210689
#define OFF_CNT  6307841
#define OFF_MEAN 6316033

// d_out scratch (all consumed before the real outputs overwrite, stream-ordered):
//   zhp  [0 .. 2097152) floats        — permuted fp16 z, dead after dist
//   chp  [2097152 .. 3145728) floats  — permuted fp16 codebook, dead after dist
//   cand [4210692 .. 6307844) floats  — u64[16384*64] top-2 keys; inside CB region
#define POFF_ZHP  0
#define POFF_CHP  2097152
#define POFF_CAND 4210692

// workspace layout (bytes)
#define WS_COUNTS 0        // f32[8192]
#define WS_CNORM  32768    // f32[8192]
#define WS_LOSSP  65536    // f32[4096] -> ends 81920
#define WS_N      81920    // f32
#define WS_MEAN   98304    // f32[8192*256] = 8388608 -> ends 8486912

typedef _Float16 half8 __attribute__((ext_vector_type(8)));
typedef _Float16 half4 __attribute__((ext_vector_type(4)));
typedef float f32x4 __attribute__((ext_vector_type(4)));

// ---------------- prep: convert z + cb to permuted fp16 planes, cnorm, zero meanAcc ----------------
// zhp granule order: [zblk(128)][kc(8)][gk(4)][r(128)][8 halfs]
// chp granule order: [cblk(32)][kc(8)][gk(4)][r(256)][8 halfs]
__global__ __launch_bounds__(256) void prep_kernel(const float* __restrict__ z,
                                                   const float* __restrict__ cb,
                                                   _Float16* __restrict__ zhp,
                                                   _Float16* __restrict__ chp,
                                                   float* __restrict__ cnorm,
                                                   float* __restrict__ meanAcc) {
    int b = blockIdx.x;
    if (b < 2048) {                       // ---- z convert: one granule per thread
        int G = b * 256 + threadIdx.x;
        int row = G >> 5, c8 = G & 31;
        const float4* s = (const float4*)(z + (size_t)row * DIM + c8 * 8);
        float4 x = s[0], y = s[1];
        float v[8] = {x.x, x.y, x.z, x.w, y.x, y.y, y.z, y.w};
        half8 h;
        #pragma unroll
        for (int i = 0; i < 8; ++i) h[i] = (_Float16)v[i];
        int zblk = row >> 7, r = row & 127, kc = c8 >> 2, gk = c8 & 3;
        size_t o = ((size_t)((zblk * 8 + kc) * 4 + gk) * 128 + r) * 8;
        *(half8*)(zhp + o) = h;
    } else if (b < 4096) {                // ---- cb convert + fp64 cnorm: one wave per row
        int w = threadIdx.x >> 6, lane = threadIdx.x & 63;
        int row = (b - 2048) * 4 + w;
        float4 v = *(const float4*)(cb + (size_t)row * DIM + lane * 4);
        half4 h;
        h[0] = (_Float16)v.x; h[1] = (_Float16)v.y; h[2] = (_Float16)v.z; h[3] = (_Float16)v.w;
        int c8 = lane >> 1, pos = (lane & 1) * 4;
        int cblk = row >> 8, r = row & 255, kc = c8 >> 2, gk = c8 & 3;
        size_t o = ((size_t)((cblk * 8 + kc) * 4 + gk) * 256 + r) * 8 + pos;
        *(half4*)(chp + o) = h;
        double s = (double)v.x * v.x + (double)v.y * v.y + (double)v.z * v.z + (double)v.w * v.w;
        #pragma unroll
        for (int off = 32; off; off >>= 1) s += __shfl_down(s, off, 64);
        if (lane == 0) cnorm[row] = (float)s;
    } else {                              // ---- zero meanAcc: 8 floats per thread
        int g = (b - 4096) * 256 + threadIdx.x;
        float4 zero = {0.f, 0.f, 0.f, 0.f};
        float4* p = (float4*)(meanAcc + (size_t)g * 8);
        p[0] = zero; p[1] = zero;
    }
}

// ---------------- distance screen: LDS-free direct-global MFMA, 2 code-blocks per WG ----------------
// block = 64 z x 512 codes (two 256-code cbY tiles processed sequentially);
// wave = 64 codes x 64 z per tile (4i x 4j of 16x16x32_f16).
// cbY1's kc=0 loads are issued BEFORE cbY0's epilogue -> epilogue VALU hides load latency.
__global__ __launch_bounds__(256, 3) void dist_kernel(const _Float16* __restrict__ zhp,
                                                      const _Float16* __restrict__ chp,
                                                      const float* __restrict__ cnorm,
                                                      unsigned long long* __restrict__ cand) {
    __shared__ unsigned long long red[2][4][64][2];   // 8KB, double-buffered per p

    const int tid = threadIdx.x;
    const int w = tid >> 6, lane = tid & 63;
    const int c16 = lane & 15, g4 = lane >> 4;

    // XCD-bijective swizzle (4096 blocks, 8 XCDs): per XCD zbX spans 32 contiguous
    // z-blocks over all 16 cbY-pairs -> L2 set ~= chp 4MB + zhp 1MB.
    int wg = (blockIdx.x & 7) * 512 + (blockIdx.x >> 3);
    int cbP = wg & 15;      // code-block pair (2x256 codes)
    int zbX = wg >> 4;      // z block (64 rows)

    // chp halfs: cblk*65536 + kc*8192 + gk*2048 + r*8 ; r = w*64 + i*16 + c16
    // zhp halfs: zblk*32768 + kc*4096 + gk*1024 + r*8 ; r = (zbX&1)*64 + j*16 + c16
    const _Float16* Abase = chp + (size_t)(cbP * 2) * 65536 + g4 * 2048 + (w * 64 + c16) * 8;
    const _Float16* Bbase = zhp + (size_t)(zbX >> 1) * 32768 + g4 * 1024 + ((zbX & 1) * 64 + c16) * 8;

    f32x4 acc[4][4];
    #pragma unroll
    for (int i = 0; i < 4; ++i)
        #pragma unroll
        for (int j = 0; j < 4; ++j) acc[i][j] = 0.0f;

    half8 a[4], b[4], an[4], bn[4];
    #pragma unroll
    for (int i = 0; i < 4; ++i) a[i] = *(const half8*)(Abase + i * 128);
    #pragma unroll
    for (int j = 0; j < 4; ++j) b[j] = *(const half8*)(Bbase + j * 128);

    #pragma unroll
    for (int p = 0; p < 2; ++p) {
        const int cbY = cbP * 2 + p;
        const _Float16* Ap = Abase + (size_t)p * 65536;

        #pragma unroll
        for (int kc = 0; kc < 8; ++kc) {
            if (kc < 7) {
                #pragma unroll
                for (int i = 0; i < 4; ++i) an[i] = *(const half8*)(Ap + (kc + 1) * 8192 + i * 128);
                #pragma unroll
                for (int j = 0; j < 4; ++j) bn[j] = *(const half8*)(Bbase + (kc + 1) * 4096 + j * 128);
            } else if (p == 0) {
                // prefetch next code-block's kc=0 while epilogue p=0 runs
                #pragma unroll
                for (int i = 0; i < 4; ++i) an[i] = *(const half8*)(Ap + 65536 + i * 128);
                #pragma unroll
                for (int j = 0; j < 4; ++j) bn[j] = *(const half8*)(Bbase + j * 128);
            }
            #pragma unroll
            for (int i = 0; i < 4; ++i)
                #pragma unroll
                for (int j = 0; j < 4; ++j)
                    acc[i][j] = __builtin_amdgcn_mfma_f32_16x16x32_f16(a[i], b[j], acc[i][j], 0, 0, 0);
            if (kc < 7 || p == 0) {
                #pragma unroll
                for (int i = 0; i < 4; ++i) a[i] = an[i];
                #pragma unroll
                for (int j = 0; j < 4; ++j) b[j] = bn[j];
            }
        }

        // hoisted cnorm for this thread's 16 codes of tile p
        float cn[4][4];
        #pragma unroll
        for (int i = 0; i < 4; ++i)
            #pragma unroll
            for (int reg = 0; reg < 4; ++reg)
                cn[i][reg] = cnorm[cbY * 256 + w * 64 + i * 16 + g4 * 4 + reg];

        // epilogue: top-2 per (z-col, 256-code block).
        // key = raw float bits (d clamped >=0 so uint order == float order) << 32 | code
        #pragma unroll
        for (int j = 0; j < 4; ++j) {
            unsigned long long b1 = ~0ull, b2 = ~0ull;
            #pragma unroll
            for (int i = 0; i < 4; ++i) {
                #pragma unroll
                for (int reg = 0; reg < 4; ++reg) {
                    int code = cbY * 256 + w * 64 + i * 16 + g4 * 4 + reg;
                    float d = fmaf(-2.0f, acc[i][j][reg], cn[i][reg]);
                    d = fmaxf(d, 0.0f);
                    unsigned long long key = ((unsigned long long)__float_as_uint(d) << 32) | (unsigned)code;
                    if (key < b1) { b2 = b1; b1 = key; }
                    else if (key < b2) { b2 = key; }
                }
            }
            #pragma unroll
            for (int off = 16; off <= 32; off <<= 1) {
                unsigned long long o1 = __shfl_xor(b1, off), o2 = __shfl_xor(b2, off);
                unsigned long long m1 = (b1 < o1) ? b1 : o1;
                unsigned long long hi = (b1 < o1) ? o1 : b1;
                unsigned long long m2 = (b2 < o2) ? b2 : o2;
                b1 = m1; b2 = (m2 < hi) ? m2 : hi;
            }
            if (lane < 16) { red[p][w][j * 16 + lane][0] = b1; red[p][w][j * 16 + lane][1] = b2; }
        }
        __syncthreads();
        if (tid < 64) {
            unsigned long long b1 = ~0ull, b2 = ~0ull;
            #pragma unroll
            for (int t = 0; t < 4; ++t) {
                unsigned long long o1 = red[p][t][tid][0], o2 = red[p][t][tid][1];
                unsigned long long m1 = (b1 < o1) ? b1 : o1;
                unsigned long long hi = (b1 < o1) ? o1 : b1;
                unsigned long long m2 = (b2 < o2) ? b2 : o2;
                b1 = m1; b2 = (m2 < hi) ? m2 : hi;
            }
            size_t base = (size_t)(zbX * 64 + tid) * 64 + cbY * 2;
            cand[base] = b1;
            cand[base + 1] = b2;
        }
        if (p == 0) {
            #pragma unroll
            for (int i = 0; i < 4; ++i)
                #pragma unroll
                for (int j = 0; j < 4; ++j) acc[i][j] = 0.0f;
        }
    }
}

__device__ inline float decode_key(unsigned e) {
    return __uint_as_float(e);   // keys store raw non-negative float bits
}

// ---------------- rescore (fp64 within margin) + assign, fused ----------------
__global__ __launch_bounds__(256) void rescore_assign_kernel(const float* __restrict__ z,
                                                             const float* __restrict__ cb,
                                                             const unsigned long long* __restrict__ cand,
                                                             float* __restrict__ zq_out,
                                                             float* __restrict__ idx_out,
                                                             float* __restrict__ counts,
                                                             float* __restrict__ meanAcc,
                                                             float* __restrict__ lossPart) {
    __shared__ float lred[4];
    int w = threadIdx.x >> 6, lane = threadIdx.x & 63;
    int row = blockIdx.x * 4 + w;
    unsigned long long k64 = cand[(size_t)row * 64 + lane];
    unsigned long long m = k64;
    #pragma unroll
    for (int off = 32; off; off >>= 1) {
        unsigned long long o = __shfl_xor(m, off);
        if (o < m) m = o;
    }
    float fmin = decode_key((unsigned)(m >> 32));
    float f = decode_key((unsigned)(k64 >> 32));
    unsigned long long mask = __ballot(f <= fmin + 0.25f);   // margin >> 2x screen error (0.024)

    float4 zv = *(const float4*)(z + (size_t)row * DIM + lane * 4);
    double bd = 1e300;
    int bc = 0x7fffffff;
    while (mask) {
        int src = __ffsll((unsigned long long)mask) - 1;
        mask &= mask - 1;
        int code = (int)(unsigned)__shfl(k64, src);
        float4 c4 = *(const float4*)(cb + (size_t)code * DIM + lane * 4);
        double d0 = (double)zv.x - c4.x, d1 = (double)zv.y - c4.y;
        double d2 = (double)zv.z - c4.z, d3 = (double)zv.w - c4.w;
        double s = d0 * d0 + d1 * d1 + d2 * d2 + d3 * d3;
        #pragma unroll
        for (int off = 32; off; off >>= 1) s += __shfl_xor(s, off);
        if (s < bd || (s == bd && code < bc)) { bd = s; bc = code; }
    }

    float4 cv = *(const float4*)(cb + (size_t)bc * DIM + lane * 4);
    *(float4*)(zq_out + (size_t)row * DIM + lane * 4) = cv;
    float d0 = zv.x - cv.x, d1 = zv.y - cv.y, d2 = zv.z - cv.z, d3 = zv.w - cv.w;
    float ls = d0 * d0 + d1 * d1 + d2 * d2 + d3 * d3;
    #pragma unroll
    for (int off = 32; off; off >>= 1) ls += __shfl_down(ls, off, 64);
    float* mp = meanAcc + (size_t)bc * DIM + lane * 4;
    atomicAdd(mp + 0, zv.x);
    atomicAdd(mp + 1, zv.y);
    atomicAdd(mp + 2, zv.z);
    atomicAdd(mp + 3, zv.w);
    if (lane == 0) {
        idx_out[row] = (float)bc;
        atomicAdd(counts + bc, 1.0f);
        lred[w] = ls;
    }
    __syncthreads();
    if (threadIdx.x == 0)
        lossPart[blockIdx.x] = lred[0] + lred[1] + lred[2] + lred[3];
}

// ---------------- count finalize + n + loss scalar ----------------
__global__ __launch_bounds__(1024) void count_final_kernel(const float* __restrict__ ema_count,
                                                           const float* __restrict__ counts,
                                                           float* __restrict__ newCount_out,
                                                           float* __restrict__ nOut,
                                                           const float* __restrict__ lossPart,
                                                           float* __restrict__ loss_out) {
    __shared__ float sred[1024];
    const float OMD = (float)(1.0 - 0.99);
    int tid = threadIdx.x;
    float s = 0.f;
    #pragma unroll
    for (int k = tid; k < K_CODES; k += 1024) {
        float nc = 0.99f * ema_count[k] + OMD * counts[k];
        newCount_out[k] = nc;
        s += nc;
    }
    sred[tid] = s;
    __syncthreads();
    for (int off = 512; off; off >>= 1) {
        if (tid < off) sred[tid] += sred[tid + off];
        __syncthreads();
    }
    if (tid == 0) nOut[0] = sred[0];
    __syncthreads();
    float L = lossPart[tid] + lossPart[tid + 1024] + lossPart[tid + 2048] + lossPart[tid + 3072];
    sred[tid] = L;
    __syncthreads();
    for (int off = 512; off; off >>= 1) {
        if (tid < off) sred[tid] += sred[tid + off];
        __syncthreads();
    }
    if (tid == 0) loss_out[0] = 1.25f * sred[0] / 4194304.0f;
}

// ---------------- mean finalize + new codebook ----------------
__global__ __launch_bounds__(256) void final_kernel(const float* __restrict__ ema_mean,
                                                    const float* __restrict__ meanAcc,
                                                    const float* __restrict__ newCount,
                                                    const float* __restrict__ nPtr,
                                                    float* __restrict__ newMean_out,
                                                    float* __restrict__ newCb_out) {
    const float OMD = (float)(1.0 - 0.99);
    int g = blockIdx.x * 256 + threadIdx.x;
    int k = g >> 6;
    int c4 = (g & 63) * 4;
    float n = nPtr[0];
    float nc = newCount[k];
    float cs = (nc + 1e-5f) / (n + (float)(K_CODES * 1e-5)) * n;
    size_t base = (size_t)k * DIM + c4;
    float4 em = *(const float4*)(ema_mean + base);
    float4 mm = *(const float4*)(meanAcc + base);
    float4 nm;
    nm.x = 0.99f * em.x + OMD * mm.x;
    nm.y = 0.99f * em.y + OMD * mm.y;
    nm.z = 0.99f * em.z + OMD * mm.z;
    nm.w = 0.99f * em.w + OMD * mm.w;
    *(float4*)(newMean_out + base) = nm;
    float4 cbv;
    cbv.x = nm.x / cs;
    cbv.y = nm.y / cs;
    cbv.z = nm.z / cs;
    cbv.w = nm.w / cs;
    *(float4*)(newCb_out + base) = cbv;
}

extern "C" void kernel_launch(void* const* d_in, const int* in_sizes, int n_in,
                              void* d_out, int out_size, void* d_ws, size_t ws_size,
                              hipStream_t stream) {
    const float* z         = (const float*)d_in[0];
    const float* cb        = (const float*)d_in[1];
    const float* ema_count = (const float*)d_in[2];
    const float* ema_mean  = (const float*)d_in[3];
    float* out = (float*)d_out;
    char* ws = (char*)d_ws;

    float* counts   = (float*)(ws + WS_COUNTS);
    float* cnorm    = (float*)(ws + WS_CNORM);
    float* lossPart = (float*)(ws + WS_LOSSP);
    float* nPtr     = (float*)(ws + WS_N);
    float* meanAcc  = (float*)(ws + WS_MEAN);

    _Float16* zhp = (_Float16*)(out + POFF_ZHP);
    _Float16* chp = (_Float16*)(out + POFF_CHP);
    unsigned long long* cand = (unsigned long long*)(out + POFF_CAND);

    hipMemsetAsync(ws, 0, WS_MEAN, stream);   // counts/cnorm/lossPart/n only

    prep_kernel<<<5120, 256, 0, stream>>>(z, cb, zhp, chp, cnorm, meanAcc);
    dist_kernel<<<4096, 256, 0, stream>>>(zhp, chp, cnorm, cand);
    rescore_assign_kernel<<<N_ROWS / 4, 256, 0, stream>>>(z, cb, cand, out + OFF_ZQ,
                                                          out + OFF_IDX, counts, meanAcc, lossPart);
    count_final_kernel<<<1, 1024, 0, stream>>>(ema_count, counts, out + OFF_CNT, nPtr,
                                               lossPart, out + OFF_LOSS);
    final_kernel<<<(K_CODES * DIM / 4) / 256, 256, 0, stream>>>(ema_mean, meanAcc,
                                                                out + OFF_CNT, nPtr,
                                                                out + OFF_MEAN, out + OFF_CB);
}

// Round 9
// 232.030 us; speedup vs baseline: 1.1005x; 1.1005x over previous
//
#include <hip/hip_runtime.h>

// ---- problem constants ----
#define N_ROWS 16384   // 8*16*128
#define DIM    256
#define K_CODES 8192

// output layout (flat float32, return order)
#define OFF_ZQ   0
#define OFF_LOSS 4194304
#define OFF_IDX  4194305
#define OFF_CB   4210689
#define OFF_CNT  6307841
#define OFF_MEAN 6316033

// d_out scratch (all consumed before the real outputs overwrite, stream-ordered):
//   zhp  [0 .. 2097152) floats        — permuted fp16 z, dead after dist
//   chp  [2097152 .. 3145728) floats  — permuted fp16 codebook, dead after dist
//   cand [4210692 .. 6307844) floats  — u64[16384*64] top-2 keys; inside CB region
#define POFF_ZHP  0
#define POFF_CHP  2097152
#define POFF_CAND 4210692

// workspace layout (bytes)
#define WS_COUNTS 0        // f32[8192]
#define WS_CNORM  32768    // f32[8192]
#define WS_LOSSP  65536    // f32[4096] -> ends 81920
#define WS_N      81920    // f32
#define WS_MEAN   98304    // f32[8192*256] = 8388608 -> ends 8486912

typedef _Float16 half8 __attribute__((ext_vector_type(8)));
typedef _Float16 half4 __attribute__((ext_vector_type(4)));
typedef float f32x4 __attribute__((ext_vector_type(4)));

// ---------------- prep: convert z + cb to permuted fp16 planes, cnorm, zero meanAcc ----------------
// zhp granule order: [zblk(128)][kc(8)][gk(4)][r(128)][8 halfs]
// chp granule order: [cblk(32)][kc(8)][gk(4)][r(256)][8 halfs]
__global__ __launch_bounds__(256) void prep_kernel(const float* __restrict__ z,
                                                   const float* __restrict__ cb,
                                                   _Float16* __restrict__ zhp,
                                                   _Float16* __restrict__ chp,
                                                   float* __restrict__ cnorm,
                                                   float* __restrict__ meanAcc) {
    int b = blockIdx.x;
    if (b < 2048) {                       // ---- z convert: one granule per thread
        int G = b * 256 + threadIdx.x;
        int row = G >> 5, c8 = G & 31;
        const float4* s = (const float4*)(z + (size_t)row * DIM + c8 * 8);
        float4 x = s[0], y = s[1];
        float v[8] = {x.x, x.y, x.z, x.w, y.x, y.y, y.z, y.w};
        half8 h;
        #pragma unroll
        for (int i = 0; i < 8; ++i) h[i] = (_Float16)v[i];
        int zblk = row >> 7, r = row & 127, kc = c8 >> 2, gk = c8 & 3;
        size_t o = ((size_t)((zblk * 8 + kc) * 4 + gk) * 128 + r) * 8;
        *(half8*)(zhp + o) = h;
    } else if (b < 4096) {                // ---- cb convert + fp64 cnorm: one wave per row
        int w = threadIdx.x >> 6, lane = threadIdx.x & 63;
        int row = (b - 2048) * 4 + w;
        float4 v = *(const float4*)(cb + (size_t)row * DIM + lane * 4);
        half4 h;
        h[0] = (_Float16)v.x; h[1] = (_Float16)v.y; h[2] = (_Float16)v.z; h[3] = (_Float16)v.w;
        int c8 = lane >> 1, pos = (lane & 1) * 4;
        int cblk = row >> 8, r = row & 255, kc = c8 >> 2, gk = c8 & 3;
        size_t o = ((size_t)((cblk * 8 + kc) * 4 + gk) * 256 + r) * 8 + pos;
        *(half4*)(chp + o) = h;
        double s = (double)v.x * v.x + (double)v.y * v.y + (double)v.z * v.z + (double)v.w * v.w;
        #pragma unroll
        for (int off = 32; off; off >>= 1) s += __shfl_down(s, off, 64);
        if (lane == 0) cnorm[row] = (float)s;
    } else {                              // ---- zero meanAcc: 8 floats per thread
        int g = (b - 4096) * 256 + threadIdx.x;
        float4 zero = {0.f, 0.f, 0.f, 0.f};
        float4* p = (float4*)(meanAcc + (size_t)g * 8);
        p[0] = zero; p[1] = zero;
    }
}

// ---------------- distance screen: LDS-free direct-global MFMA, top-2 per 256-code block ----------------
// block = 256 codes x 64 z, 4 waves; wave = 64 codes x 64 z (4i x 4j of 16x16x32_f16).
// L2-window swizzle: per XCD, cbY changes SLOWLY (outer) while zbX walks 32 contiguous
// z-blocks -> same-XCD time-window = A-slice 128KB + B 1MB + cand 128KB << 4MB L2.
__global__ __launch_bounds__(256, 3) void dist_kernel(const _Float16* __restrict__ zhp,
                                                      const _Float16* __restrict__ chp,
                                                      const float* __restrict__ cnorm,
                                                      unsigned long long* __restrict__ cand) {
    __shared__ unsigned long long red[4][64][2];   // 4KB, epilogue only

    const int tid = threadIdx.x;
    const int w = tid >> 6, lane = tid & 63;
    const int c16 = lane & 15, g4 = lane >> 4;

    int b = blockIdx.x;
    int xcd = b & 7;
    int wgx = b >> 3;               // 0..1023 within XCD (round-robin dispatch)
    int cbY = wgx >> 5;             // 0..31  code block (256 codes) — slow
    int zbX = xcd * 32 + (wgx & 31);// 0..255 z block (64 rows) — fast, XCD-contiguous

    f32x4 acc[4][4];
    #pragma unroll
    for (int i = 0; i < 4; ++i)
        #pragma unroll
        for (int j = 0; j < 4; ++j) acc[i][j] = 0.0f;

    // chp halfs: cblk*65536 + kc*8192 + gk*2048 + r*8 ; r = w*64 + i*16 + c16
    // zhp halfs: zblk*32768 + kc*4096 + gk*1024 + r*8 ; r = (zbX&1)*64 + j*16 + c16
    const _Float16* Abase = chp + (size_t)cbY * 65536 + g4 * 2048 + (w * 64 + c16) * 8;
    const _Float16* Bbase = zhp + (size_t)(zbX >> 1) * 32768 + g4 * 1024 + ((zbX & 1) * 64 + c16) * 8;

    half8 a[4], b_[4], an[4], bn[4];
    #pragma unroll
    for (int i = 0; i < 4; ++i) a[i] = *(const half8*)(Abase + i * 128);
    #pragma unroll
    for (int j = 0; j < 4; ++j) b_[j] = *(const half8*)(Bbase + j * 128);

    #pragma unroll
    for (int kc = 0; kc < 8; ++kc) {
        if (kc < 7) {
            #pragma unroll
            for (int i = 0; i < 4; ++i) an[i] = *(const half8*)(Abase + (kc + 1) * 8192 + i * 128);
            #pragma unroll
            for (int j = 0; j < 4; ++j) bn[j] = *(const half8*)(Bbase + (kc + 1) * 4096 + j * 128);
        }
        #pragma unroll
        for (int i = 0; i < 4; ++i)
            #pragma unroll
            for (int j = 0; j < 4; ++j)
                acc[i][j] = __builtin_amdgcn_mfma_f32_16x16x32_f16(a[i], b_[j], acc[i][j], 0, 0, 0);
        if (kc < 7) {
            #pragma unroll
            for (int i = 0; i < 4; ++i) a[i] = an[i];
            #pragma unroll
            for (int j = 0; j < 4; ++j) b_[j] = bn[j];
        }
    }

    // hoisted cnorm for this thread's 16 codes
    float cn[4][4];
    #pragma unroll
    for (int i = 0; i < 4; ++i)
        #pragma unroll
        for (int reg = 0; reg < 4; ++reg)
            cn[i][reg] = cnorm[cbY * 256 + w * 64 + i * 16 + g4 * 4 + reg];

    // epilogue: top-2 per (z-col, 256-code block); C/D: col=lane&15 (z), row=(lane>>4)*4+reg (code)
    // key = raw float bits (d clamped >=0 so uint order == float order) << 32 | code
    #pragma unroll
    for (int j = 0; j < 4; ++j) {
        unsigned long long b1 = ~0ull, b2 = ~0ull;
        #pragma unroll
        for (int i = 0; i < 4; ++i) {
            #pragma unroll
            for (int reg = 0; reg < 4; ++reg) {
                int code = cbY * 256 + w * 64 + i * 16 + g4 * 4 + reg;
                float d = fmaf(-2.0f, acc[i][j][reg], cn[i][reg]);
                d = fmaxf(d, 0.0f);
                unsigned long long key = ((unsigned long long)__float_as_uint(d) << 32) | (unsigned)code;
                if (key < b1) { b2 = b1; b1 = key; }
                else if (key < b2) { b2 = key; }
            }
        }
        #pragma unroll
        for (int off = 16; off <= 32; off <<= 1) {
            unsigned long long o1 = __shfl_xor(b1, off), o2 = __shfl_xor(b2, off);
            unsigned long long m1 = (b1 < o1) ? b1 : o1;
            unsigned long long hi = (b1 < o1) ? o1 : b1;
            unsigned long long m2 = (b2 < o2) ? b2 : o2;
            b1 = m1; b2 = (m2 < hi) ? m2 : hi;
        }
        if (lane < 16) { red[w][j * 16 + lane][0] = b1; red[w][j * 16 + lane][1] = b2; }
    }
    __syncthreads();
    if (tid < 64) {
        unsigned long long b1 = ~0ull, b2 = ~0ull;
        #pragma unroll
        for (int t = 0; t < 4; ++t) {
            unsigned long long o1 = red[t][tid][0], o2 = red[t][tid][1];
            unsigned long long m1 = (b1 < o1) ? b1 : o1;
            unsigned long long hi = (b1 < o1) ? o1 : b1;
            unsigned long long m2 = (b2 < o2) ? b2 : o2;
            b1 = m1; b2 = (m2 < hi) ? m2 : hi;
        }
        size_t base = (size_t)(zbX * 64 + tid) * 64 + cbY * 2;
        cand[base] = b1;
        cand[base + 1] = b2;
    }
}

__device__ inline float decode_key(unsigned e) {
    return __uint_as_float(e);   // keys store raw non-negative float bits
}

// ---------------- rescore (fp64 within margin) + assign, fused ----------------
__global__ __launch_bounds__(256) void rescore_assign_kernel(const float* __restrict__ z,
                                                             const float* __restrict__ cb,
                                                             const unsigned long long* __restrict__ cand,
                                                             float* __restrict__ zq_out,
                                                             float* __restrict__ idx_out,
                                                             float* __restrict__ counts,
                                                             float* __restrict__ meanAcc,
                                                             float* __restrict__ lossPart) {
    __shared__ float lred[4];
    int w = threadIdx.x >> 6, lane = threadIdx.x & 63;
    int row = blockIdx.x * 4 + w;
    unsigned long long k64 = cand[(size_t)row * 64 + lane];
    unsigned long long m = k64;
    #pragma unroll
    for (int off = 32; off; off >>= 1) {
        unsigned long long o = __shfl_xor(m, off);
        if (o < m) m = o;
    }
    float fmin = decode_key((unsigned)(m >> 32));
    float f = decode_key((unsigned)(k64 >> 32));
    unsigned long long mask = __ballot(f <= fmin + 0.25f);   // margin >> screen error bound

    float4 zv = *(const float4*)(z + (size_t)row * DIM + lane * 4);
    double bd = 1e300;
    int bc = 0x7fffffff;
    while (mask) {
        int src = __ffsll((unsigned long long)mask) - 1;
        mask &= mask - 1;
        int code = (int)(unsigned)__shfl(k64, src);
        float4 c4 = *(const float4*)(cb + (size_t)code * DIM + lane * 4);
        double d0 = (double)zv.x - c4.x, d1 = (double)zv.y - c4.y;
        double d2 = (double)zv.z - c4.z, d3 = (double)zv.w - c4.w;
        double s = d0 * d0 + d1 * d1 + d2 * d2 + d3 * d3;
        #pragma unroll
        for (int off = 32; off; off >>= 1) s += __shfl_xor(s, off);
        if (s < bd || (s == bd && code < bc)) { bd = s; bc = code; }
    }

    float4 cv = *(const float4*)(cb + (size_t)bc * DIM + lane * 4);
    *(float4*)(zq_out + (size_t)row * DIM + lane * 4) = cv;
    float d0 = zv.x - cv.x, d1 = zv.y - cv.y, d2 = zv.z - cv.z, d3 = zv.w - cv.w;
    float ls = d0 * d0 + d1 * d1 + d2 * d2 + d3 * d3;
    #pragma unroll
    for (int off = 32; off; off >>= 1) ls += __shfl_down(ls, off, 64);
    float* mp = meanAcc + (size_t)bc * DIM + lane * 4;
    atomicAdd(mp + 0, zv.x);
    atomicAdd(mp + 1, zv.y);
    atomicAdd(mp + 2, zv.z);
    atomicAdd(mp + 3, zv.w);
    if (lane == 0) {
        idx_out[row] = (float)bc;
        atomicAdd(counts + bc, 1.0f);
        lred[w] = ls;
    }
    __syncthreads();
    if (threadIdx.x == 0)
        lossPart[blockIdx.x] = lred[0] + lred[1] + lred[2] + lred[3];
}

// ---------------- count finalize + n + loss scalar ----------------
__global__ __launch_bounds__(1024) void count_final_kernel(const float* __restrict__ ema_count,
                                                           const float* __restrict__ counts,
                                                           float* __restrict__ newCount_out,
                                                           float* __restrict__ nOut,
                                                           const float* __restrict__ lossPart,
                                                           float* __restrict__ loss_out) {
    __shared__ float sred[1024];
    const float OMD = (float)(1.0 - 0.99);
    int tid = threadIdx.x;
    float s = 0.f;
    #pragma unroll
    for (int k = tid; k < K_CODES; k += 1024) {
        float nc = 0.99f * ema_count[k] + OMD * counts[k];
        newCount_out[k] = nc;
        s += nc;
    }
    sred[tid] = s;
    __syncthreads();
    for (int off = 512; off; off >>= 1) {
        if (tid < off) sred[tid] += sred[tid + off];
        __syncthreads();
    }
    if (tid == 0) nOut[0] = sred[0];
    __syncthreads();
    float L = lossPart[tid] + lossPart[tid + 1024] + lossPart[tid + 2048] + lossPart[tid + 3072];
    sred[tid] = L;
    __syncthreads();
    for (int off = 512; off; off >>= 1) {
        if (tid < off) sred[tid] += sred[tid + off];
        __syncthreads();
    }
    if (tid == 0) loss_out[0] = 1.25f * sred[0] / 4194304.0f;
}

// ---------------- mean finalize + new codebook ----------------
__global__ __launch_bounds__(256) void final_kernel(const float* __restrict__ ema_mean,
                                                    const float* __restrict__ meanAcc,
                                                    const float* __restrict__ newCount,
                                                    const float* __restrict__ nPtr,
                                                    float* __restrict__ newMean_out,
                                                    float* __restrict__ newCb_out) {
    const float OMD = (float)(1.0 - 0.99);
    int g = blockIdx.x * 256 + threadIdx.x;
    int k = g >> 6;
    int c4 = (g & 63) * 4;
    float n = nPtr[0];
    float nc = newCount[k];
    float cs = (nc + 1e-5f) / (n + (float)(K_CODES * 1e-5)) * n;
    size_t base = (size_t)k * DIM + c4;
    float4 em = *(const float4*)(ema_mean + base);
    float4 mm = *(const float4*)(meanAcc + base);
    float4 nm;
    nm.x = 0.99f * em.x + OMD * mm.x;
    nm.y = 0.99f * em.y + OMD * mm.y;
    nm.z = 0.99f * em.z + OMD * mm.z;
    nm.w = 0.99f * em.w + OMD * mm.w;
    *(float4*)(newMean_out + base) = nm;
    float4 cbv;
    cbv.x = nm.x / cs;
    cbv.y = nm.y / cs;
    cbv.z = nm.z / cs;
    cbv.w = nm.w / cs;
    *(float4*)(newCb_out + base) = cbv;
}

extern "C" void kernel_launch(void* const* d_in, const int* in_sizes, int n_in,
                              void* d_out, int out_size, void* d_ws, size_t ws_size,
                              hipStream_t stream) {
    const float* z         = (const float*)d_in[0];
    const float* cb        = (const float*)d_in[1];
    const float* ema_count = (const float*)d_in[2];
    const float* ema_mean  = (const float*)d_in[3];
    float* out = (float*)d_out;
    char* ws = (char*)d_ws;

    float* counts   = (float*)(ws + WS_COUNTS);
    float* cnorm    = (float*)(ws + WS_CNORM);
    float* lossPart = (float*)(ws + WS_LOSSP);
    float* nPtr     = (float*)(ws + WS_N);
    float* meanAcc  = (float*)(ws + WS_MEAN);

    _Float16* zhp = (_Float16*)(out + POFF_ZHP);
    _Float16* chp = (_Float16*)(out + POFF_CHP);
    unsigned long long* cand = (unsigned long long*)(out + POFF_CAND);

    hipMemsetAsync(ws, 0, WS_MEAN, stream);   // counts/cnorm/lossPart/n only

    prep_kernel<<<5120, 256, 0, stream>>>(z, cb, zhp, chp, cnorm, meanAcc);
    dist_kernel<<<8192, 256, 0, stream>>>(zhp, chp, cnorm, cand);
    rescore_assign_kernel<<<N_ROWS / 4, 256, 0, stream>>>(z, cb, cand, out + OFF_ZQ,
                                                          out + OFF_IDX, counts, meanAcc, lossPart);
    count_final_kernel<<<1, 1024, 0, stream>>>(ema_count, counts, out + OFF_CNT, nPtr,
                                               lossPart, out + OFF_LOSS);
    final_kernel<<<(K_CODES * DIM / 4) / 256, 256, 0, stream>>>(ema_mean, meanAcc,
                                                                out + OFF_CNT, nPtr,
                                                                out + OFF_MEAN, out + OFF_CB);
}

// Round 10
// 229.839 us; speedup vs baseline: 1.1110x; 1.0095x over previous
//
#include <hip/hip_runtime.h>

// ---- problem constants ----
#define N_ROWS 16384   // 8*16*128
#define DIM    256
#define K_CODES 8192

// output layout (flat float32, return order)
#define OFF_ZQ   0
#define OFF_LOSS 4194304
#define OFF_IDX  4194305
#define OFF_CB   4210689
#define OFF_CNT  6307841
#define OFF_MEAN 6316033

// d_out scratch (all consumed before the real outputs overwrite, stream-ordered):
//   zhp  [0 .. 2097152) floats        — permuted fp16 z, dead after dist
//   chp  [2097152 .. 3145728) floats  — permuted fp16 codebook, dead after dist
//   cand [4210692 .. 6307844) floats  — u64[32][16384][2] (cbY-major!) top-2 keys
#define POFF_ZHP  0
#define POFF_CHP  2097152
#define POFF_CAND 4210692

// workspace layout (bytes)
#define WS_COUNTS 0        // f32[8192]
#define WS_CNORM  32768    // f32[8192]
#define WS_LOSSP  65536    // f32[4096] -> ends 81920
#define WS_N      81920    // f32
#define WS_MEAN   98304    // f32[8192*256] = 8388608 -> ends 8486912

typedef _Float16 half8 __attribute__((ext_vector_type(8)));
typedef _Float16 half4 __attribute__((ext_vector_type(4)));
typedef float f32x4 __attribute__((ext_vector_type(4)));

// ---------------- prep: convert z + cb to permuted fp16 planes, cnorm, zero meanAcc ----------------
// zhp granule order: [zblk(128)][kc(8)][gk(4)][r(128)][8 halfs]
// chp granule order: [cblk(32)][kc(8)][gk(4)][r(256)][8 halfs]
__global__ __launch_bounds__(256) void prep_kernel(const float* __restrict__ z,
                                                   const float* __restrict__ cb,
                                                   _Float16* __restrict__ zhp,
                                                   _Float16* __restrict__ chp,
                                                   float* __restrict__ cnorm,
                                                   float* __restrict__ meanAcc) {
    int b = blockIdx.x;
    if (b < 2048) {                       // ---- z convert: one granule per thread
        int G = b * 256 + threadIdx.x;
        int row = G >> 5, c8 = G & 31;
        const float4* s = (const float4*)(z + (size_t)row * DIM + c8 * 8);
        float4 x = s[0], y = s[1];
        float v[8] = {x.x, x.y, x.z, x.w, y.x, y.y, y.z, y.w};
        half8 h;
        #pragma unroll
        for (int i = 0; i < 8; ++i) h[i] = (_Float16)v[i];
        int zblk = row >> 7, r = row & 127, kc = c8 >> 2, gk = c8 & 3;
        size_t o = ((size_t)((zblk * 8 + kc) * 4 + gk) * 128 + r) * 8;
        *(half8*)(zhp + o) = h;
    } else if (b < 4096) {                // ---- cb convert + fp64 cnorm: one wave per row
        int w = threadIdx.x >> 6, lane = threadIdx.x & 63;
        int row = (b - 2048) * 4 + w;
        float4 v = *(const float4*)(cb + (size_t)row * DIM + lane * 4);
        half4 h;
        h[0] = (_Float16)v.x; h[1] = (_Float16)v.y; h[2] = (_Float16)v.z; h[3] = (_Float16)v.w;
        int c8 = lane >> 1, pos = (lane & 1) * 4;
        int cblk = row >> 8, r = row & 255, kc = c8 >> 2, gk = c8 & 3;
        size_t o = ((size_t)((cblk * 8 + kc) * 4 + gk) * 256 + r) * 8 + pos;
        *(half4*)(chp + o) = h;
        double s = (double)v.x * v.x + (double)v.y * v.y + (double)v.z * v.z + (double)v.w * v.w;
        #pragma unroll
        for (int off = 32; off; off >>= 1) s += __shfl_down(s, off, 64);
        if (lane == 0) cnorm[row] = (float)s;
    } else {                              // ---- zero meanAcc: 8 floats per thread
        int g = (b - 4096) * 256 + threadIdx.x;
        float4 zero = {0.f, 0.f, 0.f, 0.f};
        float4* p = (float4*)(meanAcc + (size_t)g * 8);
        p[0] = zero; p[1] = zero;
    }
}

// ---------------- distance screen: LDS-free direct-global MFMA, top-2 per 256-code block ----------------
// block = 256 codes x 64 z, 4 waves; wave = 64 codes x 64 z (4i x 4j of 16x16x32_f16).
// Read swizzle (R9, proven 37MB fetch): per XCD cbY slow, zbX walks 32 contiguous blocks.
// Write locality (new): cand is cbY-major -> each WG writes one contiguous 1KB chunk.
__global__ __launch_bounds__(256, 3) void dist_kernel(const _Float16* __restrict__ zhp,
                                                      const _Float16* __restrict__ chp,
                                                      const float* __restrict__ cnorm,
                                                      unsigned long long* __restrict__ cand) {
    __shared__ unsigned long long red[4][64][2];   // 4KB, epilogue only

    const int tid = threadIdx.x;
    const int w = tid >> 6, lane = tid & 63;
    const int c16 = lane & 15, g4 = lane >> 4;

    int b = blockIdx.x;
    int xcd = b & 7;
    int wgx = b >> 3;               // 0..1023 within XCD (round-robin dispatch)
    int cbY = wgx >> 5;             // 0..31  code block (256 codes) — slow
    int zbX = xcd * 32 + (wgx & 31);// 0..255 z block (64 rows) — fast, XCD-contiguous

    f32x4 acc[4][4];
    #pragma unroll
    for (int i = 0; i < 4; ++i)
        #pragma unroll
        for (int j = 0; j < 4; ++j) acc[i][j] = 0.0f;

    // chp halfs: cblk*65536 + kc*8192 + gk*2048 + r*8 ; r = w*64 + i*16 + c16
    // zhp halfs: zblk*32768 + kc*4096 + gk*1024 + r*8 ; r = (zbX&1)*64 + j*16 + c16
    const _Float16* Abase = chp + (size_t)cbY * 65536 + g4 * 2048 + (w * 64 + c16) * 8;
    const _Float16* Bbase = zhp + (size_t)(zbX >> 1) * 32768 + g4 * 1024 + ((zbX & 1) * 64 + c16) * 8;

    half8 a[4], b_[4], an[4], bn[4];
    #pragma unroll
    for (int i = 0; i < 4; ++i) a[i] = *(const half8*)(Abase + i * 128);
    #pragma unroll
    for (int j = 0; j < 4; ++j) b_[j] = *(const half8*)(Bbase + j * 128);

    #pragma unroll
    for (int kc = 0; kc < 8; ++kc) {
        if (kc < 7) {
            #pragma unroll
            for (int i = 0; i < 4; ++i) an[i] = *(const half8*)(Abase + (kc + 1) * 8192 + i * 128);
            #pragma unroll
            for (int j = 0; j < 4; ++j) bn[j] = *(const half8*)(Bbase + (kc + 1) * 4096 + j * 128);
        }
        #pragma unroll
        for (int i = 0; i < 4; ++i)
            #pragma unroll
            for (int j = 0; j < 4; ++j)
                acc[i][j] = __builtin_amdgcn_mfma_f32_16x16x32_f16(a[i], b_[j], acc[i][j], 0, 0, 0);
        if (kc < 7) {
            #pragma unroll
            for (int i = 0; i < 4; ++i) a[i] = an[i];
            #pragma unroll
            for (int j = 0; j < 4; ++j) b_[j] = bn[j];
        }
    }

    // hoisted cnorm for this thread's 16 codes
    float cn[4][4];
    #pragma unroll
    for (int i = 0; i < 4; ++i)
        #pragma unroll
        for (int reg = 0; reg < 4; ++reg)
            cn[i][reg] = cnorm[cbY * 256 + w * 64 + i * 16 + g4 * 4 + reg];

    // epilogue: top-2 per (z-col, 256-code block); C/D: col=lane&15 (z), row=(lane>>4)*4+reg (code)
    // key = raw float bits (d clamped >=0 so uint order == float order) << 32 | code
    #pragma unroll
    for (int j = 0; j < 4; ++j) {
        unsigned long long b1 = ~0ull, b2 = ~0ull;
        #pragma unroll
        for (int i = 0; i < 4; ++i) {
            #pragma unroll
            for (int reg = 0; reg < 4; ++reg) {
                int code = cbY * 256 + w * 64 + i * 16 + g4 * 4 + reg;
                float d = fmaf(-2.0f, acc[i][j][reg], cn[i][reg]);
                d = fmaxf(d, 0.0f);
                unsigned long long key = ((unsigned long long)__float_as_uint(d) << 32) | (unsigned)code;
                if (key < b1) { b2 = b1; b1 = key; }
                else if (key < b2) { b2 = key; }
            }
        }
        #pragma unroll
        for (int off = 16; off <= 32; off <<= 1) {
            unsigned long long o1 = __shfl_xor(b1, off), o2 = __shfl_xor(b2, off);
            unsigned long long m1 = (b1 < o1) ? b1 : o1;
            unsigned long long hi = (b1 < o1) ? o1 : b1;
            unsigned long long m2 = (b2 < o2) ? b2 : o2;
            b1 = m1; b2 = (m2 < hi) ? m2 : hi;
        }
        if (lane < 16) { red[w][j * 16 + lane][0] = b1; red[w][j * 16 + lane][1] = b2; }
    }
    __syncthreads();
    if (tid < 64) {
        unsigned long long b1 = ~0ull, b2 = ~0ull;
        #pragma unroll
        for (int t = 0; t < 4; ++t) {
            unsigned long long o1 = red[t][tid][0], o2 = red[t][tid][1];
            unsigned long long m1 = (b1 < o1) ? b1 : o1;
            unsigned long long hi = (b1 < o1) ? o1 : b1;
            unsigned long long m2 = (b2 < o2) ? b2 : o2;
            b1 = m1; b2 = (m2 < hi) ? m2 : hi;
        }
        // cbY-major: contiguous 1KB per workgroup, full-line single-writer
        size_t base = (size_t)cbY * (N_ROWS * 2) + (size_t)(zbX * 64 + tid) * 2;
        cand[base] = b1;
        cand[base + 1] = b2;
    }
}

__device__ inline float decode_key(unsigned e) {
    return __uint_as_float(e);   // keys store raw non-negative float bits
}

// ---------------- rescore (fp64 within margin) + assign, fused ----------------
__global__ __launch_bounds__(256) void rescore_assign_kernel(const float* __restrict__ z,
                                                             const float* __restrict__ cb,
                                                             const unsigned long long* __restrict__ cand,
                                                             float* __restrict__ zq_out,
                                                             float* __restrict__ idx_out,
                                                             float* __restrict__ counts,
                                                             float* __restrict__ meanAcc,
                                                             float* __restrict__ lossPart) {
    __shared__ float lred[4];
    int w = threadIdx.x >> 6, lane = threadIdx.x & 63;
    int row = blockIdx.x * 4 + w;
    // cbY-major gather: lane -> (cbY = lane>>1, slot = lane&1)
    unsigned long long k64 = cand[(size_t)(lane >> 1) * (N_ROWS * 2) + (size_t)row * 2 + (lane & 1)];
    unsigned long long m = k64;
    #pragma unroll
    for (int off = 32; off; off >>= 1) {
        unsigned long long o = __shfl_xor(m, off);
        if (o < m) m = o;
    }
    float fmin = decode_key((unsigned)(m >> 32));
    float f = decode_key((unsigned)(k64 >> 32));
    unsigned long long mask = __ballot(f <= fmin + 0.25f);   // margin >> screen error bound

    float4 zv = *(const float4*)(z + (size_t)row * DIM + lane * 4);
    double bd = 1e300;
    int bc = 0x7fffffff;
    while (mask) {
        int src = __ffsll((unsigned long long)mask) - 1;
        mask &= mask - 1;
        int code = (int)(unsigned)__shfl(k64, src);
        float4 c4 = *(const float4*)(cb + (size_t)code * DIM + lane * 4);
        double d0 = (double)zv.x - c4.x, d1 = (double)zv.y - c4.y;
        double d2 = (double)zv.z - c4.z, d3 = (double)zv.w - c4.w;
        double s = d0 * d0 + d1 * d1 + d2 * d2 + d3 * d3;
        #pragma unroll
        for (int off = 32; off; off >>= 1) s += __shfl_xor(s, off);
        if (s < bd || (s == bd && code < bc)) { bd = s; bc = code; }
    }

    float4 cv = *(const float4*)(cb + (size_t)bc * DIM + lane * 4);
    *(float4*)(zq_out + (size_t)row * DIM + lane * 4) = cv;
    float d0 = zv.x - cv.x, d1 = zv.y - cv.y, d2 = zv.z - cv.z, d3 = zv.w - cv.w;
    float ls = d0 * d0 + d1 * d1 + d2 * d2 + d3 * d3;
    #pragma unroll
    for (int off = 32; off; off >>= 1) ls += __shfl_down(ls, off, 64);
    float* mp = meanAcc + (size_t)bc * DIM + lane * 4;
    atomicAdd(mp + 0, zv.x);
    atomicAdd(mp + 1, zv.y);
    atomicAdd(mp + 2, zv.z);
    atomicAdd(mp + 3, zv.w);
    if (lane == 0) {
        idx_out[row] = (float)bc;
        atomicAdd(counts + bc, 1.0f);
        lred[w] = ls;
    }
    __syncthreads();
    if (threadIdx.x == 0)
        lossPart[blockIdx.x] = lred[0] + lred[1] + lred[2] + lred[3];
}

// ---------------- count finalize + n + loss scalar ----------------
__global__ __launch_bounds__(1024) void count_final_kernel(const float* __restrict__ ema_count,
                                                           const float* __restrict__ counts,
                                                           float* __restrict__ newCount_out,
                                                           float* __restrict__ nOut,
                                                           const float* __restrict__ lossPart,
                                                           float* __restrict__ loss_out) {
    __shared__ float sred[1024];
    const float OMD = (float)(1.0 - 0.99);
    int tid = threadIdx.x;
    float s = 0.f;
    #pragma unroll
    for (int k = tid; k < K_CODES; k += 1024) {
        float nc = 0.99f * ema_count[k] + OMD * counts[k];
        newCount_out[k] = nc;
        s += nc;
    }
    sred[tid] = s;
    __syncthreads();
    for (int off = 512; off; off >>= 1) {
        if (tid < off) sred[tid] += sred[tid + off];
        __syncthreads();
    }
    if (tid == 0) nOut[0] = sred[0];
    __syncthreads();
    float L = lossPart[tid] + lossPart[tid + 1024] + lossPart[tid + 2048] + lossPart[tid + 3072];
    sred[tid] = L;
    __syncthreads();
    for (int off = 512; off; off >>= 1) {
        if (tid < off) sred[tid] += sred[tid + off];
        __syncthreads();
    }
    if (tid == 0) loss_out[0] = 1.25f * sred[0] / 4194304.0f;
}

// ---------------- mean finalize + new codebook ----------------
__global__ __launch_bounds__(256) void final_kernel(const float* __restrict__ ema_mean,
                                                    const float* __restrict__ meanAcc,
                                                    const float* __restrict__ newCount,
                                                    const float* __restrict__ nPtr,
                                                    float* __restrict__ newMean_out,
                                                    float* __restrict__ newCb_out) {
    const float OMD = (float)(1.0 - 0.99);
    int g = blockIdx.x * 256 + threadIdx.x;
    int k = g >> 6;
    int c4 = (g & 63) * 4;
    float n = nPtr[0];
    float nc = newCount[k];
    float cs = (nc + 1e-5f) / (n + (float)(K_CODES * 1e-5)) * n;
    size_t base = (size_t)k * DIM + c4;
    float4 em = *(const float4*)(ema_mean + base);
    float4 mm = *(const float4*)(meanAcc + base);
    float4 nm;
    nm.x = 0.99f * em.x + OMD * mm.x;
    nm.y = 0.99f * em.y + OMD * mm.y;
    nm.z = 0.99f * em.z + OMD * mm.z;
    nm.w = 0.99f * em.w + OMD * mm.w;
    *(float4*)(newMean_out + base) = nm;
    float4 cbv;
    cbv.x = nm.x / cs;
    cbv.y = nm.y / cs;
    cbv.z = nm.z / cs;
    cbv.w = nm.w / cs;
    *(float4*)(newCb_out + base) = cbv;
}

extern "C" void kernel_launch(void* const* d_in, const int* in_sizes, int n_in,
                              void* d_out, int out_size, void* d_ws, size_t ws_size,
                              hipStream_t stream) {
    const float* z         = (const float*)d_in[0];
    const float* cb        = (const float*)d_in[1];
    const float* ema_count = (const float*)d_in[2];
    const float* ema_mean  = (const float*)d_in[3];
    float* out = (float*)d_out;
    char* ws = (char*)d_ws;

    float* counts   = (float*)(ws + WS_COUNTS);
    float* cnorm    = (float*)(ws + WS_CNORM);
    float* lossPart = (float*)(ws + WS_LOSSP);
    float* nPtr     = (float*)(ws + WS_N);
    float* meanAcc  = (float*)(ws + WS_MEAN);

    _Float16* zhp = (_Float16*)(out + POFF_ZHP);
    _Float16* chp = (_Float16*)(out + POFF_CHP);
    unsigned long long* cand = (unsigned long long*)(out + POFF_CAND);

    hipMemsetAsync(ws, 0, WS_MEAN, stream);   // counts/cnorm/lossPart/n only

    prep_kernel<<<5120, 256, 0, stream>>>(z, cb, zhp, chp, cnorm, meanAcc);
    dist_kernel<<<8192, 256, 0, stream>>>(zhp, chp, cnorm, cand);
    rescore_assign_kernel<<<N_ROWS / 4, 256, 0, stream>>>(z, cb, cand, out + OFF_ZQ,
                                                          out + OFF_IDX, counts, meanAcc, lossPart);
    count_final_kernel<<<1, 1024, 0, stream>>>(ema_count, counts, out + OFF_CNT, nPtr,
                                               lossPart, out + OFF_LOSS);
    final_kernel<<<(K_CODES * DIM / 4) / 256, 256, 0, stream>>>(ema_mean, meanAcc,
                                                                out + OFF_CNT, nPtr,
                                                                out + OFF_MEAN, out + OFF_CB);
}

// Round 11
// 194.752 us; speedup vs baseline: 1.3111x; 1.1802x over previous
//
#include <hip/hip_runtime.h>

// ---- problem constants ----
#define N_ROWS 16384   // 8*16*128
#define DIM    256
#define K_CODES 8192

// output layout (flat float32, return order)
#define OFF_ZQ   0
#define OFF_LOSS 4194304
#define OFF_IDX  4194305
#define OFF_CB   4210689
#define OFF_CNT  6307841
#define OFF_MEAN 6316033

// d_out scratch (all consumed before the real outputs overwrite, stream-ordered):
//   zhp  [0 .. 2097152) floats        — permuted fp16 z, dead after dist
//   chp  [2097152 .. 3145728) floats  — permuted fp16 codebook, dead after dist
//   cand [4210692 .. 5259268) floats  — u32[32][16384][2] (cbY-major) top-2 keys
#define POFF_ZHP  0
#define POFF_CHP  2097152
#define POFF_CAND 4210692

// workspace layout (bytes)
#define WS_COUNTS 0        // f32[8192]
#define WS_CNORM  32768    // f32[8192]
#define WS_LOSSP  65536    // f32[4096] -> ends 81920
#define WS_N      81920    // f32
#define WS_MEAN   98304    // f32[8192*256] = 8388608 -> ends 8486912

typedef _Float16 half8 __attribute__((ext_vector_type(8)));
typedef _Float16 half4 __attribute__((ext_vector_type(4)));
typedef float f32x4 __attribute__((ext_vector_type(4)));

// ---------------- prep: convert z + cb to permuted fp16 planes, cnorm, zero meanAcc ----------------
// zhp granule order: [zblk(128)][kc(8)][gk(4)][r(128)][8 halfs]
// chp granule order: [cblk(32)][kc(8)][gk(4)][r(256)][8 halfs]
__global__ __launch_bounds__(256) void prep_kernel(const float* __restrict__ z,
                                                   const float* __restrict__ cb,
                                                   _Float16* __restrict__ zhp,
                                                   _Float16* __restrict__ chp,
                                                   float* __restrict__ cnorm,
                                                   float* __restrict__ meanAcc) {
    int b = blockIdx.x;
    if (b < 2048) {                       // ---- z convert: one granule per thread
        int G = b * 256 + threadIdx.x;
        int row = G >> 5, c8 = G & 31;
        const float4* s = (const float4*)(z + (size_t)row * DIM + c8 * 8);
        float4 x = s[0], y = s[1];
        float v[8] = {x.x, x.y, x.z, x.w, y.x, y.y, y.z, y.w};
        half8 h;
        #pragma unroll
        for (int i = 0; i < 8; ++i) h[i] = (_Float16)v[i];
        int zblk = row >> 7, r = row & 127, kc = c8 >> 2, gk = c8 & 3;
        size_t o = ((size_t)((zblk * 8 + kc) * 4 + gk) * 128 + r) * 8;
        *(half8*)(zhp + o) = h;
    } else if (b < 4096) {                // ---- cb convert + fp64 cnorm: one wave per row
        int w = threadIdx.x >> 6, lane = threadIdx.x & 63;
        int row = (b - 2048) * 4 + w;
        float4 v = *(const float4*)(cb + (size_t)row * DIM + lane * 4);
        half4 h;
        h[0] = (_Float16)v.x; h[1] = (_Float16)v.y; h[2] = (_Float16)v.z; h[3] = (_Float16)v.w;
        int c8 = lane >> 1, pos = (lane & 1) * 4;
        int cblk = row >> 8, r = row & 255, kc = c8 >> 2, gk = c8 & 3;
        size_t o = ((size_t)((cblk * 8 + kc) * 4 + gk) * 256 + r) * 8 + pos;
        *(half4*)(chp + o) = h;
        double s = (double)v.x * v.x + (double)v.y * v.y + (double)v.z * v.z + (double)v.w * v.w;
        #pragma unroll
        for (int off = 32; off; off >>= 1) s += __shfl_down(s, off, 64);
        if (lane == 0) cnorm[row] = (float)s;
    } else {                              // ---- zero meanAcc: 8 floats per thread
        int g = (b - 4096) * 256 + threadIdx.x;
        float4 zero = {0.f, 0.f, 0.f, 0.f};
        float4* p = (float4*)(meanAcc + (size_t)g * 8);
        p[0] = zero; p[1] = zero;
    }
}

// ---------------- distance screen: direct-global MFMA, pinned 1-deep prefetch ----------------
// block = 256 codes x 64 z, 4 waves; wave = 64 codes x 64 z (4i x 4j of 16x16x32_f16).
// Read swizzle (R9-proven, 31MB fetch): per XCD cbY slow, zbX walks 32 contiguous blocks.
// sched_barrier(0) after each prefetch cluster pins loads 1 iteration ahead of MFMAs
// (without it the compiler sinks the loads: VGPR=84 proved the pipeline was dead).
// Epilogue keys: u32 = (float bits of clamped dist & 0xFFFFFF00) | 8-bit local code.
__global__ __launch_bounds__(256, 3) void dist_kernel(const _Float16* __restrict__ zhp,
                                                      const _Float16* __restrict__ chp,
                                                      const float* __restrict__ cnorm,
                                                      unsigned* __restrict__ cand) {
    __shared__ unsigned red[4][64][2];   // 2KB, epilogue only

    const int tid = threadIdx.x;
    const int w = tid >> 6, lane = tid & 63;
    const int c16 = lane & 15, g4 = lane >> 4;

    int b = blockIdx.x;
    int xcd = b & 7;
    int wgx = b >> 3;               // 0..1023 within XCD (round-robin dispatch)
    int cbY = wgx >> 5;             // 0..31  code block (256 codes) — slow
    int zbX = xcd * 32 + (wgx & 31);// 0..255 z block (64 rows) — fast, XCD-contiguous

    f32x4 acc[4][4];
    #pragma unroll
    for (int i = 0; i < 4; ++i)
        #pragma unroll
        for (int j = 0; j < 4; ++j) acc[i][j] = 0.0f;

    // chp halfs: cblk*65536 + kc*8192 + gk*2048 + r*8 ; r = w*64 + i*16 + c16
    // zhp halfs: zblk*32768 + kc*4096 + gk*1024 + r*8 ; r = (zbX&1)*64 + j*16 + c16
    const _Float16* Abase = chp + (size_t)cbY * 65536 + g4 * 2048 + (w * 64 + c16) * 8;
    const _Float16* Bbase = zhp + (size_t)(zbX >> 1) * 32768 + g4 * 1024 + ((zbX & 1) * 64 + c16) * 8;

    half8 a[4], b_[4], an[4], bn[4];
    #pragma unroll
    for (int i = 0; i < 4; ++i) a[i] = *(const half8*)(Abase + i * 128);
    #pragma unroll
    for (int j = 0; j < 4; ++j) b_[j] = *(const half8*)(Bbase + j * 128);

    #pragma unroll
    for (int kc = 0; kc < 8; ++kc) {
        if (kc < 7) {
            #pragma unroll
            for (int i = 0; i < 4; ++i) an[i] = *(const half8*)(Abase + (kc + 1) * 8192 + i * 128);
            #pragma unroll
            for (int j = 0; j < 4; ++j) bn[j] = *(const half8*)(Bbase + (kc + 1) * 4096 + j * 128);
            __builtin_amdgcn_sched_barrier(0);   // prefetch must not sink past the MFMAs
        }
        #pragma unroll
        for (int i = 0; i < 4; ++i)
            #pragma unroll
            for (int j = 0; j < 4; ++j)
                acc[i][j] = __builtin_amdgcn_mfma_f32_16x16x32_f16(a[i], b_[j], acc[i][j], 0, 0, 0);
        if (kc < 7) {
            __builtin_amdgcn_sched_barrier(0);   // register rotation stays behind MFMAs
            #pragma unroll
            for (int i = 0; i < 4; ++i) a[i] = an[i];
            #pragma unroll
            for (int j = 0; j < 4; ++j) b_[j] = bn[j];
        }
    }

    // hoisted cnorm for this thread's 16 codes
    float cn[4][4];
    #pragma unroll
    for (int i = 0; i < 4; ++i)
        #pragma unroll
        for (int reg = 0; reg < 4; ++reg)
            cn[i][reg] = cnorm[cbY * 256 + w * 64 + i * 16 + g4 * 4 + reg];

    // epilogue: top-2 per (z-col, 256-code block); C/D: col=lane&15 (z), row=(lane>>4)*4+reg (code)
    // u32 key: upper 24 bits = clamped-dist float bits (trunc err <= 0.03), low 8 = w*64-local code
    #pragma unroll
    for (int j = 0; j < 4; ++j) {
        unsigned b1 = 0xFFFFFFFFu, b2 = 0xFFFFFFFFu;
        #pragma unroll
        for (int i = 0; i < 4; ++i) {
            #pragma unroll
            for (int reg = 0; reg < 4; ++reg) {
                unsigned id = (unsigned)(w * 64 + i * 16 + g4 * 4 + reg);   // 8-bit local code
                float d = fmaf(-2.0f, acc[i][j][reg], cn[i][reg]);
                d = fmaxf(d, 0.0f);
                unsigned key = (__float_as_uint(d) & 0xFFFFFF00u) | id;
                if (key < b1) { b2 = b1; b1 = key; }
                else if (key < b2) { b2 = key; }
            }
        }
        #pragma unroll
        for (int off = 16; off <= 32; off <<= 1) {
            unsigned o1 = __shfl_xor(b1, off), o2 = __shfl_xor(b2, off);
            unsigned m1 = (b1 < o1) ? b1 : o1;
            unsigned hi = (b1 < o1) ? o1 : b1;
            unsigned m2 = (b2 < o2) ? b2 : o2;
            b1 = m1; b2 = (m2 < hi) ? m2 : hi;
        }
        if (lane < 16) { red[w][j * 16 + lane][0] = b1; red[w][j * 16 + lane][1] = b2; }
    }
    __syncthreads();
    if (tid < 64) {
        unsigned b1 = 0xFFFFFFFFu, b2 = 0xFFFFFFFFu;
        #pragma unroll
        for (int t = 0; t < 4; ++t) {
            unsigned o1 = red[t][tid][0], o2 = red[t][tid][1];
            unsigned m1 = (b1 < o1) ? b1 : o1;
            unsigned hi = (b1 < o1) ? o1 : b1;
            unsigned m2 = (b2 < o2) ? b2 : o2;
            b1 = m1; b2 = (m2 < hi) ? m2 : hi;
        }
        // cbY-major: contiguous 512B per workgroup
        size_t base = (size_t)cbY * (N_ROWS * 2) + (size_t)(zbX * 64 + tid) * 2;
        *(uint2*)(cand + base) = make_uint2(b1, b2);
    }
}

// ---------------- rescore (fp64 within margin) + assign, fused ----------------
__global__ __launch_bounds__(256) void rescore_assign_kernel(const float* __restrict__ z,
                                                             const float* __restrict__ cb,
                                                             const unsigned* __restrict__ cand,
                                                             float* __restrict__ zq_out,
                                                             float* __restrict__ idx_out,
                                                             float* __restrict__ counts,
                                                             float* __restrict__ meanAcc,
                                                             float* __restrict__ lossPart) {
    __shared__ float lred[4];
    int w = threadIdx.x >> 6, lane = threadIdx.x & 63;
    int row = blockIdx.x * 4 + w;
    // cbY-major gather: lane -> (cbY = lane>>1, slot = lane&1)
    int cbY = lane >> 1;
    unsigned k32 = cand[(size_t)cbY * (N_ROWS * 2) + (size_t)row * 2 + (lane & 1)];
    unsigned m = k32;
    #pragma unroll
    for (int off = 32; off; off >>= 1) {
        unsigned o = __shfl_xor(m, off);
        if (o < m) m = o;
    }
    float fmin = __uint_as_float(m & 0xFFFFFF00u);
    float f = __uint_as_float(k32 & 0xFFFFFF00u);
    int mycode = cbY * 256 + (int)(k32 & 0xFFu);
    unsigned long long mask = __ballot(f <= fmin + 0.25f);   // margin >> 2*(0.024 fp16 + 0.03 trunc)

    float4 zv = *(const float4*)(z + (size_t)row * DIM + lane * 4);
    double bd = 1e300;
    int bc = 0x7fffffff;
    while (mask) {
        int src = __ffsll((unsigned long long)mask) - 1;
        mask &= mask - 1;
        int code = __shfl(mycode, src);
        float4 c4 = *(const float4*)(cb + (size_t)code * DIM + lane * 4);
        double d0 = (double)zv.x - c4.x, d1 = (double)zv.y - c4.y;
        double d2 = (double)zv.z - c4.z, d3 = (double)zv.w - c4.w;
        double s = d0 * d0 + d1 * d1 + d2 * d2 + d3 * d3;
        #pragma unroll
        for (int off = 32; off; off >>= 1) s += __shfl_xor(s, off);
        if (s < bd || (s == bd && code < bc)) { bd = s; bc = code; }
    }

    float4 cv = *(const float4*)(cb + (size_t)bc * DIM + lane * 4);
    *(float4*)(zq_out + (size_t)row * DIM + lane * 4) = cv;
    float d0 = zv.x - cv.x, d1 = zv.y - cv.y, d2 = zv.z - cv.z, d3 = zv.w - cv.w;
    float ls = d0 * d0 + d1 * d1 + d2 * d2 + d3 * d3;
    #pragma unroll
    for (int off = 32; off; off >>= 1) ls += __shfl_down(ls, off, 64);
    float* mp = meanAcc + (size_t)bc * DIM + lane * 4;
    atomicAdd(mp + 0, zv.x);
    atomicAdd(mp + 1, zv.y);
    atomicAdd(mp + 2, zv.z);
    atomicAdd(mp + 3, zv.w);
    if (lane == 0) {
        idx_out[row] = (float)bc;
        atomicAdd(counts + bc, 1.0f);
        lred[w] = ls;
    }
    __syncthreads();
    if (threadIdx.x == 0)
        lossPart[blockIdx.x] = lred[0] + lred[1] + lred[2] + lred[3];
}

// ---------------- count finalize + n + loss scalar ----------------
__global__ __launch_bounds__(1024) void count_final_kernel(const float* __restrict__ ema_count,
                                                           const float* __restrict__ counts,
                                                           float* __restrict__ newCount_out,
                                                           float* __restrict__ nOut,
                                                           const float* __restrict__ lossPart,
                                                           float* __restrict__ loss_out) {
    __shared__ float sred[1024];
    const float OMD = (float)(1.0 - 0.99);
    int tid = threadIdx.x;
    float s = 0.f;
    #pragma unroll
    for (int k = tid; k < K_CODES; k += 1024) {
        float nc = 0.99f * ema_count[k] + OMD * counts[k];
        newCount_out[k] = nc;
        s += nc;
    }
    sred[tid] = s;
    __syncthreads();
    for (int off = 512; off; off >>= 1) {
        if (tid < off) sred[tid] += sred[tid + off];
        __syncthreads();
    }
    if (tid == 0) nOut[0] = sred[0];
    __syncthreads();
    float L = lossPart[tid] + lossPart[tid + 1024] + lossPart[tid + 2048] + lossPart[tid + 3072];
    sred[tid] = L;
    __syncthreads();
    for (int off = 512; off; off >>= 1) {
        if (tid < off) sred[tid] += sred[tid + off];
        __syncthreads();
    }
    if (tid == 0) loss_out[0] = 1.25f * sred[0] / 4194304.0f;
}

// ---------------- mean finalize + new codebook ----------------
__global__ __launch_bounds__(256) void final_kernel(const float* __restrict__ ema_mean,
                                                    const float* __restrict__ meanAcc,
                                                    const float* __restrict__ newCount,
                                                    const float* __restrict__ nPtr,
                                                    float* __restrict__ newMean_out,
                                                    float* __restrict__ newCb_out) {
    const float OMD = (float)(1.0 - 0.99);
    int g = blockIdx.x * 256 + threadIdx.x;
    int k = g >> 6;
    int c4 = (g & 63) * 4;
    float n = nPtr[0];
    float nc = newCount[k];
    float cs = (nc + 1e-5f) / (n + (float)(K_CODES * 1e-5)) * n;
    size_t base = (size_t)k * DIM + c4;
    float4 em = *(const float4*)(ema_mean + base);
    float4 mm = *(const float4*)(meanAcc + base);
    float4 nm;
    nm.x = 0.99f * em.x + OMD * mm.x;
    nm.y = 0.99f * em.y + OMD * mm.y;
    nm.z = 0.99f * em.z + OMD * mm.z;
    nm.w = 0.99f * em.w + OMD * mm.w;
    *(float4*)(newMean_out + base) = nm;
    float4 cbv;
    cbv.x = nm.x / cs;
    cbv.y = nm.y / cs;
    cbv.z = nm.z / cs;
    cbv.w = nm.w / cs;
    *(float4*)(newCb_out + base) = cbv;
}

extern "C" void kernel_launch(void* const* d_in, const int* in_sizes, int n_in,
                              void* d_out, int out_size, void* d_ws, size_t ws_size,
                              hipStream_t stream) {
    const float* z         = (const float*)d_in[0];
    const float* cb        = (const float*)d_in[1];
    const float* ema_count = (const float*)d_in[2];
    const float* ema_mean  = (const float*)d_in[3];
    float* out = (float*)d_out;
    char* ws = (char*)d_ws;

    float* counts   = (float*)(ws + WS_COUNTS);
    float* cnorm    = (float*)(ws + WS_CNORM);
    float* lossPart = (float*)(ws + WS_LOSSP);
    float* nPtr     = (float*)(ws + WS_N);
    float* meanAcc  = (float*)(ws + WS_MEAN);

    _Float16* zhp = (_Float16*)(out + POFF_ZHP);
    _Float16* chp = (_Float16*)(out + POFF_CHP);
    unsigned* cand = (unsigned*)(out + POFF_CAND);

    hipMemsetAsync(ws, 0, WS_MEAN, stream);   // counts/cnorm/lossPart/n only

    prep_kernel<<<5120, 256, 0, stream>>>(z, cb, zhp, chp, cnorm, meanAcc);
    dist_kernel<<<8192, 256, 0, stream>>>(zhp, chp, cnorm, cand);
    rescore_assign_kernel<<<N_ROWS / 4, 256, 0, stream>>>(z, cb, cand, out + OFF_ZQ,
                                                          out + OFF_IDX, counts, meanAcc, lossPart);
    count_final_kernel<<<1, 1024, 0, stream>>>(ema_count, counts, out + OFF_CNT, nPtr,
                                               lossPart, out + OFF_LOSS);
    final_kernel<<<(K_CODES * DIM / 4) / 256, 256, 0, stream>>>(ema_mean, meanAcc,
                                                                out + OFF_CNT, nPtr,
                                                                out + OFF_MEAN, out + OFF_CB);
}